// Round 6
// baseline (109.186 us; speedup 1.0000x reference)
//
#include <hip/hip_runtime.h>

// MHA forward: x[8,1024,768] fp32; Wq/Wk/Wv[12,768,64] fp32 -> out[8,1024,768] fp32
// cvt x->f16, cvt W->f16T, QKV proj (f16 MFMA, global_load_lds dbuf staging, XOR-swizzled LDS),
// flash attn: swapped-operand MFMA (S^T = K Q^T, O^T = V^T P^T), in-lane softmax, dbuf K/V.

#define Bq 8
#define Sq 1024
#define Dq 768
#define Hq 12
#define DHq 64

typedef _Float16 f16;
typedef f16 f16x8 __attribute__((ext_vector_type(8)));
typedef float f32x4 __attribute__((ext_vector_type(4)));

#define MFMA16(a, b, c) __builtin_amdgcn_mfma_f32_16x16x32_f16(a, b, c, 0, 0, 0)

// 0.125 (1/sqrt(64)) * log2(e): folded into Q so attn works in exp2 domain
#define QSCL 0.1803368801111244f

#if __has_builtin(__builtin_amdgcn_exp2f)
#define EXP2(x) __builtin_amdgcn_exp2f(x)
#else
#define EXP2(x) exp2f(x)
#endif

__device__ __forceinline__ void gload16(const f16* g, f16* l) {
  __builtin_amdgcn_global_load_lds(
      (const __attribute__((address_space(1))) void*)g,
      (__attribute__((address_space(3))) void*)l, 16, 0, 0);
}

// ---------- convert x (fp32 -> f16), 8 elems/thread ----------
__global__ __launch_bounds__(256) void cvt_x_kernel(const float* __restrict__ x,
                                                    f16* __restrict__ xh) {
  int i = blockIdx.x * 256 + threadIdx.x;
  const float4* src = reinterpret_cast<const float4*>(x) + i * 2;
  float4 a = src[0], b = src[1];
  f16x8 o;
  o[0] = (f16)a.x; o[1] = (f16)a.y; o[2] = (f16)a.z; o[3] = (f16)a.w;
  o[4] = (f16)b.x; o[5] = (f16)b.y; o[6] = (f16)b.z; o[7] = (f16)b.w;
  *reinterpret_cast<f16x8*>(xh + i * 8) = o;
}

// ---------- convert W -> WT f16, layout [w(0=q,1=k,2=v)][h][e(64)][k(768)] ----------
__global__ __launch_bounds__(256) void cvt_w_kernel(const float* __restrict__ Wq,
                                                    const float* __restrict__ Wk,
                                                    const float* __restrict__ Wv,
                                                    f16* __restrict__ WT) {
  int o = blockIdx.x * 256 + threadIdx.x;
  int k = o % Dq;
  int t2 = o / Dq;
  int e = t2 & 63;
  int hh = (t2 >> 6) % Hq;
  int w = (t2 >> 6) / Hq;
  const float* W = (w == 0) ? Wq : (w == 1) ? Wk : Wv;
  WT[o] = (f16)(W[(hh * Dq + k) * DHq + e]);
}

// ---------- QKV projection: tile 128x192, BK=32, global_load_lds dbuf, 2Mx2N waves ----------
// LDS layout (linear, XOR-swizzled): row r of a tile holds 4x 16B col-groups; logical
// col-group cg lives at physical slot cg ^ (r&3). DMA writes linearly with the global
// SOURCE pre-swizzled; fragment reads apply the same XOR (rule: both sides or neither).
__global__ __launch_bounds__(256) void proj_kernel(const f16* __restrict__ xh,
                                                   const f16* __restrict__ WT,
                                                   f16* __restrict__ Q,
                                                   f16* __restrict__ K,
                                                   f16* __restrict__ Vt) {
  __shared__ __align__(1024) f16 smem[20480];  // 40960 B: A dbuf 2x4096 @0, B dbuf 2x6144 @8192

  const int mt = blockIdx.x;  // 0..63
  const int h = blockIdx.y;   // 0..11
  const int row0 = mt * 128;
  const int t = threadIdx.x;
  const int wv = t >> 6;
  const int lane = t & 63;
  const int g = lane >> 4;
  const int ql = lane & 15;
  const int wvm = wv >> 1, wvn = wv & 1;

  // staging geometry: one gload16 covers 16 rows (64 B/row at BK=32)
  const int lr = lane >> 2;                  // 0..15: row within chunk
  const int scg = (lane & 3) ^ (lr & 3);     // pre-swizzled source col-group

  const f16* xsrc = xh + (size_t)row0 * Dq;
  const f16* wsrc = WT + (size_t)h * DHq * Dq;

  f32x4 acc[4][6] = {};

  auto STAGE = [&](int buf, int k0) {
    f16* sA = smem + buf * 4096;
    f16* sB = smem + 8192 + buf * 6144;
#pragma unroll
    for (int i = 0; i < 2; i++) {  // A: rows wv*32 + i*16 + lr
      int r = wv * 32 + i * 16 + lr;
      gload16(xsrc + (size_t)r * Dq + k0 + scg * 8, sA + wv * 1024 + i * 512);
    }
#pragma unroll
    for (int j = 0; j < 3; j++) {  // B: rows wv*48 + j*16 + lr
      int n = wv * 48 + j * 16 + lr;
      gload16(wsrc + ((size_t)(n >> 6) * Hq * DHq + (n & 63)) * Dq + k0 + scg * 8,
              sB + wv * 1536 + j * 512);
    }
  };

  STAGE(0, 0);
  __syncthreads();

  const int rcg = (g ^ (ql & 3)) * 8;  // swizzled read col offset (elems)
  for (int step = 0; step < 24; step++) {
    const int cur = step & 1;
    if (step < 23) STAGE(cur ^ 1, (step + 1) * 32);
    const f16* sA = smem + cur * 4096;
    const f16* sB = smem + 8192 + cur * 6144;
    f16x8 af[4], bf[6];
#pragma unroll
    for (int mf = 0; mf < 4; mf++) {
      int r = wvm * 64 + mf * 16 + ql;
      af[mf] = *reinterpret_cast<const f16x8*>(&sA[r * 32 + rcg]);
    }
#pragma unroll
    for (int nf = 0; nf < 6; nf++) {
      int n = wvn * 96 + nf * 16 + ql;
      bf[nf] = *reinterpret_cast<const f16x8*>(&sB[n * 32 + rcg]);
    }
#pragma unroll
    for (int mf = 0; mf < 4; mf++)
#pragma unroll
      for (int nf = 0; nf < 6; nf++)
        acc[mf][nf] = MFMA16(af[mf], bf[nf], acc[mf][nf]);
    __syncthreads();
  }

  const int b = row0 >> 10;
  const int s0 = row0 & 1023;
  const size_t base_sd = ((size_t)(b * Hq + h) * Sq) * DHq;

  // Q (pre-scaled) and K: [bh][s][dh]
#pragma unroll
  for (int nf = 0; nf < 6; nf++) {
    const int c = wvn * 96 + nf * 16 + ql;  // output col 0..191
    const int w = c >> 6;                   // 0=Q 1=K 2=V (wave-uniform per nf)
    if (w < 2) {
      f16* dst = (w == 0 ? Q : K);
      const float scl = (w == 0) ? QSCL : 1.0f;
      const int e = c & 63;
#pragma unroll
      for (int mf = 0; mf < 4; mf++) {
        const int sr = wvm * 64 + mf * 16 + g * 4;
#pragma unroll
        for (int r = 0; r < 4; r++)
          dst[base_sd + (size_t)(s0 + sr + r) * DHq + e] = (f16)(acc[mf][nf][r] * scl);
      }
    }
  }

  // V: transpose via smem (vbuf [64 e][136]) then coalesced write to [bh][dh][s]
  f16* vbuf = smem;  // safe: all LDS reads done (trailing barrier of step 23)
#pragma unroll
  for (int nf = 2; nf < 6; nf++) {
    if (wvn == 1) {
      const int e = (96 + nf * 16 + ql) & 63;
#pragma unroll
      for (int mf = 0; mf < 4; mf++) {
        const int sr = wvm * 64 + mf * 16 + g * 4;
        union { f16 hh[4]; uint2 u; } z;
#pragma unroll
        for (int r = 0; r < 4; r++) z.hh[r] = (f16)acc[mf][nf][r];
        *reinterpret_cast<uint2*>(&vbuf[e * 136 + sr]) = z.u;
      }
    }
  }
  __syncthreads();
#pragma unroll
  for (int i = 0; i < 4; i++) {  // 64 e-rows x 128 s = 1024 chunks of 16B
    int c = t + 256 * i;
    int e = c >> 4, p = (c & 15) * 8;
    *reinterpret_cast<uint4*>(Vt + base_sd + (size_t)e * Sq + s0 + p) =
        *reinterpret_cast<const uint4*>(vbuf + e * 136 + p);
  }
}

// ---------- flash attention: swapped-operand, dbuf K/V, 1 barrier/iter ----------
__global__ __launch_bounds__(256) void attn_kernel(const f16* __restrict__ Q,
                                                   const f16* __restrict__ K,
                                                   const f16* __restrict__ Vt,
                                                   float* __restrict__ out) {
  __shared__ __align__(16) f16 k_lds[2][64][72];   // [buf][kv][dh]
  __shared__ __align__(16) f16 vt_lds[2][64][72];  // [buf][dh][kv]

  const int blk = blockIdx.x;  // 768
  const int pr = blk & 7;
  const int bh = blk >> 3;
  const int t = threadIdx.x;
  const int wv = t >> 6;
  const int lane = t & 63;
  const int g = lane >> 4;
  const int ql = lane & 15;

  const f16* Qb = Q + (size_t)bh * Sq * DHq;
  const f16* Kb = K + (size_t)bh * Sq * DHq;
  const f16* Vtb = Vt + (size_t)bh * DHq * Sq;
  const int b = bh / Hq, h = bh % Hq;

  const int r0 = t >> 3;          // staging row 0..31 (and +32)
  const int p0 = (t & 7) * 8;     // staging col offset (f16 elems)

  for (int ph = 0; ph < 2; ph++) {
    const int mt = ph ? (15 - pr) : pr;
    const int q0 = mt * 64;
    const int qg = q0 + wv * 16 + ql;  // this lane's q row (global within bh)
    f16x8 qf0 = *reinterpret_cast<const f16x8*>(Qb + (size_t)qg * DHq + g * 8);
    f16x8 qf1 = *reinterpret_cast<const f16x8*>(Qb + (size_t)qg * DHq + 32 + g * 8);

    f32x4 o_acc[4] = {};
    float m_r = -__builtin_inff(), l_r = 0.f;

    uint4 kreg0, kreg1, vreg0, vreg1;
    // stage kt=0 directly
    kreg0 = *reinterpret_cast<const uint4*>(Kb + (size_t)r0 * DHq + p0);
    kreg1 = *reinterpret_cast<const uint4*>(Kb + (size_t)(32 + r0) * DHq + p0);
    vreg0 = *reinterpret_cast<const uint4*>(Vtb + (size_t)r0 * Sq + p0);
    vreg1 = *reinterpret_cast<const uint4*>(Vtb + (size_t)(32 + r0) * Sq + p0);
    *reinterpret_cast<uint4*>(&k_lds[0][r0][p0]) = kreg0;
    *reinterpret_cast<uint4*>(&k_lds[0][32 + r0][p0]) = kreg1;
    *reinterpret_cast<uint4*>(&vt_lds[0][r0][p0]) = vreg0;
    *reinterpret_cast<uint4*>(&vt_lds[0][32 + r0][p0]) = vreg1;
    if (mt >= 1) {  // prefetch kt=1
      kreg0 = *reinterpret_cast<const uint4*>(Kb + (size_t)(64 + r0) * DHq + p0);
      kreg1 = *reinterpret_cast<const uint4*>(Kb + (size_t)(96 + r0) * DHq + p0);
      vreg0 = *reinterpret_cast<const uint4*>(Vtb + (size_t)r0 * Sq + 64 + p0);
      vreg1 = *reinterpret_cast<const uint4*>(Vtb + (size_t)(32 + r0) * Sq + 64 + p0);
    }
    __syncthreads();

    int cur = 0;
    for (int kt = 0; kt <= mt; kt++) {
      // S^T = K Q^T : lane holds q=qg, kv_local = nt*16 + g*4 + r
      f32x4 sf[4] = {};
#pragma unroll
      for (int nt = 0; nt < 4; nt++) {
        f16x8 kf0 = *reinterpret_cast<const f16x8*>(&k_lds[cur][nt * 16 + ql][g * 8]);
        f16x8 kf1 = *reinterpret_cast<const f16x8*>(&k_lds[cur][nt * 16 + ql][32 + g * 8]);
        sf[nt] = MFMA16(kf0, qf0, sf[nt]);
        sf[nt] = MFMA16(kf1, qf1, sf[nt]);
      }

      if (kt == mt) {  // causal mask on the diagonal tile
#pragma unroll
        for (int nt = 0; nt < 4; nt++)
#pragma unroll
          for (int r = 0; r < 4; r++)
            if (nt * 16 + g * 4 + r > wv * 16 + ql) sf[nt][r] = -__builtin_inff();
      }

      // in-lane softmax (exp2 domain): lane owns 16 of 64 kv values of one q-row
      float rowmax = sf[0][0];
#pragma unroll
      for (int nt = 0; nt < 4; nt++)
#pragma unroll
        for (int r = 0; r < 4; r++) rowmax = fmaxf(rowmax, sf[nt][r]);
      rowmax = fmaxf(rowmax, __shfl_xor(rowmax, 16, 64));
      rowmax = fmaxf(rowmax, __shfl_xor(rowmax, 32, 64));
      float mnew = fmaxf(m_r, rowmax);
      float corr = EXP2(m_r - mnew);
      float p[4][4];
      float rs = 0.f;
#pragma unroll
      for (int nt = 0; nt < 4; nt++)
#pragma unroll
        for (int r = 0; r < 4; r++) {
          float pe = EXP2(sf[nt][r] - mnew);
          p[nt][r] = pe;
          rs += pe;
        }
      rs += __shfl_xor(rs, 16, 64);
      rs += __shfl_xor(rs, 32, 64);
      l_r = l_r * corr + rs;
      m_r = mnew;
#pragma unroll
      for (int nt = 0; nt < 4; nt++) {
        o_acc[nt][0] *= corr; o_acc[nt][1] *= corr;
        o_acc[nt][2] *= corr; o_acc[nt][3] *= corr;
      }

      // pack P to f16 pairs: pk[nt][p2] = P[qg][kv = nt*16 + g*4 + 2*p2 + {0,1}]
      uint32_t pk[4][2];
#pragma unroll
      for (int nt = 0; nt < 4; nt++) {
        union { f16 hh[2]; uint32_t u; } z0, z1;
        z0.hh[0] = (f16)p[nt][0]; z0.hh[1] = (f16)p[nt][1];
        z1.hh[0] = (f16)p[nt][2]; z1.hh[1] = (f16)p[nt][3];
        pk[nt][0] = z0.u; pk[nt][1] = z1.u;
      }
      // Redistribute to P^T B-fragments: shuffle BOTH nt candidates, select at dest.
      const int srcA = ((g & 1) * 2) * 16 + ql;
      const int srcB = srcA + 16;
      const bool selhi = (g >> 1) != 0;
      f16x8 pf[2];
#pragma unroll
      for (int ks = 0; ks < 2; ks++) {
        uint32_t aA0 = (uint32_t)__shfl((int)pk[2 * ks][0], srcA, 64);
        uint32_t aA1 = (uint32_t)__shfl((int)pk[2 * ks][1], srcA, 64);
        uint32_t aB0 = (uint32_t)__shfl((int)pk[2 * ks][0], srcB, 64);
        uint32_t aB1 = (uint32_t)__shfl((int)pk[2 * ks][1], srcB, 64);
        uint32_t bA0 = (uint32_t)__shfl((int)pk[2 * ks + 1][0], srcA, 64);
        uint32_t bA1 = (uint32_t)__shfl((int)pk[2 * ks + 1][1], srcA, 64);
        uint32_t bB0 = (uint32_t)__shfl((int)pk[2 * ks + 1][0], srcB, 64);
        uint32_t bB1 = (uint32_t)__shfl((int)pk[2 * ks + 1][1], srcB, 64);
        union { uint32_t w[4]; f16x8 v; } z;
        z.w[0] = selhi ? bA0 : aA0;
        z.w[1] = selhi ? bA1 : aA1;
        z.w[2] = selhi ? bB0 : aB0;
        z.w[3] = selhi ? bB1 : aB1;
        pf[ks] = z.v;
      }

      // O^T += V^T P^T : o_acc[nt] has dh = nt*16 + g*4 + r, q = qg
#pragma unroll
      for (int nt = 0; nt < 4; nt++) {
        f16x8 vf0 = *reinterpret_cast<const f16x8*>(&vt_lds[cur][nt * 16 + ql][g * 8]);
        f16x8 vf1 = *reinterpret_cast<const f16x8*>(&vt_lds[cur][nt * 16 + ql][32 + g * 8]);
        o_acc[nt] = MFMA16(vf0, pf[0], o_acc[nt]);
        o_acc[nt] = MFMA16(vf1, pf[1], o_acc[nt]);
      }

      // write next tile from regs; issue loads for kt+2
      if (kt < mt) {
        *reinterpret_cast<uint4*>(&k_lds[cur ^ 1][r0][p0]) = kreg0;
        *reinterpret_cast<uint4*>(&k_lds[cur ^ 1][32 + r0][p0]) = kreg1;
        *reinterpret_cast<uint4*>(&vt_lds[cur ^ 1][r0][p0]) = vreg0;
        *reinterpret_cast<uint4*>(&vt_lds[cur ^ 1][32 + r0][p0]) = vreg1;
        if (kt + 2 <= mt) {
          const int kv0 = (kt + 2) * 64;
          kreg0 = *reinterpret_cast<const uint4*>(Kb + (size_t)(kv0 + r0) * DHq + p0);
          kreg1 = *reinterpret_cast<const uint4*>(Kb + (size_t)(kv0 + 32 + r0) * DHq + p0);
          vreg0 = *reinterpret_cast<const uint4*>(Vtb + (size_t)r0 * Sq + kv0 + p0);
          vreg1 = *reinterpret_cast<const uint4*>(Vtb + (size_t)(32 + r0) * Sq + kv0 + p0);
        }
      }
      __syncthreads();
      cur ^= 1;
    }

    // epilogue: out[b][q][h*64 + dh], 4 consecutive dh per lane -> float4
    float rl = 1.0f / l_r;
    float* op = out + ((size_t)(b * Sq + qg)) * (Hq * DHq) + h * DHq;
#pragma unroll
    for (int nt = 0; nt < 4; nt++) {
      float4 st = { o_acc[nt][0] * rl, o_acc[nt][1] * rl,
                    o_acc[nt][2] * rl, o_acc[nt][3] * rl };
      *reinterpret_cast<float4*>(op + nt * 16 + g * 4) = st;
    }
  }
}

extern "C" void kernel_launch(void* const* d_in, const int* in_sizes, int n_in,
                              void* d_out, int out_size, void* d_ws, size_t ws_size,
                              hipStream_t stream) {
  const float* x = (const float*)d_in[0];
  const float* Wq = (const float*)d_in[1];
  const float* Wk = (const float*)d_in[2];
  const float* Wv = (const float*)d_in[3];
  float* out = (float*)d_out;

  const size_t off_xb = 0;                    // 8192*768*2      = 12,582,912
  const size_t off_wt = 12582912;             // 2304*768*2      =  3,538,944
  const size_t off_q = 16121856;              // 96*1024*64*2    = 12,582,912
  const size_t off_k = 28704768;
  const size_t off_v = 41287680;
  const size_t need = 53870592;
  if (ws_size < need) return;

  char* ws = (char*)d_ws;
  f16* xh = (f16*)(ws + off_xb);
  f16* WT = (f16*)(ws + off_wt);
  f16* Qd = (f16*)(ws + off_q);
  f16* Kd = (f16*)(ws + off_k);
  f16* Vtd = (f16*)(ws + off_v);

  cvt_x_kernel<<<3072, 256, 0, stream>>>(x, xh);
  cvt_w_kernel<<<6912, 256, 0, stream>>>(Wq, Wk, Wv, WT);
  proj_kernel<<<dim3(64, 12), 256, 0, stream>>>(xh, WT, Qd, Kd, Vtd);
  attn_kernel<<<768, 256, 0, stream>>>(Qd, Kd, Vtd, out);
}

// Round 7
// 101.916 us; speedup vs baseline: 1.0713x; 1.0713x over previous
//
#include <hip/hip_runtime.h>

// MHA forward: x[8,1024,768] fp32; Wq/Wk/Wv[12,768,64] fp32 -> out[8,1024,768] fp32
// cvt x->f16, cvt W->f16T, QKV proj (f16 MFMA, 3-buffer global_load_lds pipeline with
// counted vmcnt + raw barriers, XOR-swizzled LDS), flash attn (swapped-operand MFMA).

#define Bq 8
#define Sq 1024
#define Dq 768
#define Hq 12
#define DHq 64

typedef _Float16 f16;
typedef f16 f16x8 __attribute__((ext_vector_type(8)));
typedef float f32x4 __attribute__((ext_vector_type(4)));

#define MFMA16(a, b, c) __builtin_amdgcn_mfma_f32_16x16x32_f16(a, b, c, 0, 0, 0)

// 0.125 (1/sqrt(64)) * log2(e): folded into Q so attn works in exp2 domain
#define QSCL 0.1803368801111244f

#if __has_builtin(__builtin_amdgcn_exp2f)
#define EXP2(x) __builtin_amdgcn_exp2f(x)
#else
#define EXP2(x) exp2f(x)
#endif

__device__ __forceinline__ void gload16(const f16* g, f16* l) {
  __builtin_amdgcn_global_load_lds(
      (const __attribute__((address_space(1))) void*)g,
      (__attribute__((address_space(3))) void*)l, 16, 0, 0);
}

// ---------- convert x (fp32 -> f16), 8 elems/thread ----------
__global__ __launch_bounds__(256) void cvt_x_kernel(const float* __restrict__ x,
                                                    f16* __restrict__ xh) {
  int i = blockIdx.x * 256 + threadIdx.x;
  const float4* src = reinterpret_cast<const float4*>(x) + i * 2;
  float4 a = src[0], b = src[1];
  f16x8 o;
  o[0] = (f16)a.x; o[1] = (f16)a.y; o[2] = (f16)a.z; o[3] = (f16)a.w;
  o[4] = (f16)b.x; o[5] = (f16)b.y; o[6] = (f16)b.z; o[7] = (f16)b.w;
  *reinterpret_cast<f16x8*>(xh + i * 8) = o;
}

// ---------- convert W -> WT f16, layout [w(0=q,1=k,2=v)][h][e(64)][k(768)] ----------
__global__ __launch_bounds__(256) void cvt_w_kernel(const float* __restrict__ Wq,
                                                    const float* __restrict__ Wk,
                                                    const float* __restrict__ Wv,
                                                    f16* __restrict__ WT) {
  int o = blockIdx.x * 256 + threadIdx.x;
  int k = o % Dq;
  int t2 = o / Dq;
  int e = t2 & 63;
  int hh = (t2 >> 6) % Hq;
  int w = (t2 >> 6) / Hq;
  const float* W = (w == 0) ? Wq : (w == 1) ? Wk : Wv;
  WT[o] = (f16)(W[(hh * Dq + k) * DHq + e]);
}

// ---------- QKV projection: tile 128x192, BK=32, 3-buffer pipeline, 2Mx2N waves ----------
// LDS (linear, XOR-swizzled): logical col-group cg of row r lives at slot cg ^ (r&3).
// DMA writes linearly with the global SOURCE pre-swizzled; reads apply the same XOR.
// Pipeline: 2-deep prefetch, per-step {vmcnt(5); s_barrier; STAGE(i+2); compute(i)} —
// never drains vmcnt to 0 in the loop, so HBM latency hides under two steps of compute.
__global__ __launch_bounds__(256) void proj_kernel(const f16* __restrict__ xh,
                                                   const f16* __restrict__ WT,
                                                   f16* __restrict__ Q,
                                                   f16* __restrict__ K,
                                                   f16* __restrict__ Vt) {
  __shared__ __align__(1024) f16 smem[30720];  // 61440 B: A 3x4096 @0, B 3x6144 @12288

  const int mt = blockIdx.x;  // 0..63
  const int h = blockIdx.y;   // 0..11
  const int row0 = mt * 128;
  const int t = threadIdx.x;
  const int wv = t >> 6;
  const int lane = t & 63;
  const int g = lane >> 4;
  const int ql = lane & 15;
  const int wvm = wv >> 1, wvn = wv & 1;

  // staging geometry: one gload16 covers 16 rows (64 B/row at BK=32)
  const int lr = lane >> 2;                  // 0..15: row within chunk
  const int scg = (lane & 3) ^ (lr & 3);     // pre-swizzled source col-group

  const f16* xsrc = xh + (size_t)row0 * Dq;
  const f16* wsrc = WT + (size_t)h * DHq * Dq;

  f32x4 acc[4][6] = {};

  auto STAGE = [&](int buf, int k0) {
    f16* sA = smem + buf * 4096;
    f16* sB = smem + 12288 + buf * 6144;
#pragma unroll
    for (int i = 0; i < 2; i++) {  // A: rows wv*32 + i*16 + lr
      int r = wv * 32 + i * 16 + lr;
      gload16(xsrc + (size_t)r * Dq + k0 + scg * 8, sA + wv * 1024 + i * 512);
    }
#pragma unroll
    for (int j = 0; j < 3; j++) {  // B: rows wv*48 + j*16 + lr
      int n = wv * 48 + j * 16 + lr;
      gload16(wsrc + ((size_t)(n >> 6) * Hq * DHq + (n & 63)) * Dq + k0 + scg * 8,
              sB + wv * 1536 + j * 512);
    }
  };

  STAGE(0, 0);
  STAGE(1, 32);

  const int rcg = (g ^ (ql & 3)) * 8;  // swizzled read col offset (elems)
  int cur = 0, nx2 = 2;
  for (int step = 0; step < 24; step++) {
    // oldest 5 loads (this step's buffer) must be done; keep newer 5/10 in flight
    if (step < 23) asm volatile("s_waitcnt vmcnt(5) lgkmcnt(0)" ::: "memory");
    else           asm volatile("s_waitcnt vmcnt(0) lgkmcnt(0)" ::: "memory");
    __builtin_amdgcn_s_barrier();
    __builtin_amdgcn_sched_barrier(0);
    if (step < 22) STAGE(nx2, (step + 2) * 32);
    const f16* sA = smem + cur * 4096;
    const f16* sB = smem + 12288 + cur * 6144;
    f16x8 af[4], bf[6];
#pragma unroll
    for (int mf = 0; mf < 4; mf++) {
      int r = wvm * 64 + mf * 16 + ql;
      af[mf] = *reinterpret_cast<const f16x8*>(&sA[r * 32 + rcg]);
    }
#pragma unroll
    for (int nf = 0; nf < 6; nf++) {
      int n = wvn * 96 + nf * 16 + ql;
      bf[nf] = *reinterpret_cast<const f16x8*>(&sB[n * 32 + rcg]);
    }
#pragma unroll
    for (int mf = 0; mf < 4; mf++)
#pragma unroll
      for (int nf = 0; nf < 6; nf++)
        acc[mf][nf] = MFMA16(af[mf], bf[nf], acc[mf][nf]);
    cur = (cur == 2) ? 0 : cur + 1;
    nx2 = (nx2 == 2) ? 0 : nx2 + 1;
  }
  __syncthreads();  // all LDS reads done before smem reuse below

  const int b = row0 >> 10;
  const int s0 = row0 & 1023;
  const size_t base_sd = ((size_t)(b * Hq + h) * Sq) * DHq;

  // Q (pre-scaled) and K: [bh][s][dh]
#pragma unroll
  for (int nf = 0; nf < 6; nf++) {
    const int c = wvn * 96 + nf * 16 + ql;  // output col 0..191
    const int w = c >> 6;                   // 0=Q 1=K 2=V (wave-uniform per nf)
    if (w < 2) {
      f16* dst = (w == 0 ? Q : K);
      const float scl = (w == 0) ? QSCL : 1.0f;
      const int e = c & 63;
#pragma unroll
      for (int mf = 0; mf < 4; mf++) {
        const int sr = wvm * 64 + mf * 16 + g * 4;
#pragma unroll
        for (int r = 0; r < 4; r++)
          dst[base_sd + (size_t)(s0 + sr + r) * DHq + e] = (f16)(acc[mf][nf][r] * scl);
      }
    }
  }

  // V: transpose via smem (vbuf [64 e][136]) then coalesced write to [bh][dh][s]
  f16* vbuf = smem;
#pragma unroll
  for (int nf = 2; nf < 6; nf++) {
    if (wvn == 1) {
      const int e = (96 + nf * 16 + ql) & 63;
#pragma unroll
      for (int mf = 0; mf < 4; mf++) {
        const int sr = wvm * 64 + mf * 16 + g * 4;
        union { f16 hh[4]; uint2 u; } z;
#pragma unroll
        for (int r = 0; r < 4; r++) z.hh[r] = (f16)acc[mf][nf][r];
        *reinterpret_cast<uint2*>(&vbuf[e * 136 + sr]) = z.u;
      }
    }
  }
  __syncthreads();
#pragma unroll
  for (int i = 0; i < 4; i++) {  // 64 e-rows x 128 s = 1024 chunks of 16B
    int c = t + 256 * i;
    int e = c >> 4, p = (c & 15) * 8;
    *reinterpret_cast<uint4*>(Vt + base_sd + (size_t)e * Sq + s0 + p) =
        *reinterpret_cast<const uint4*>(vbuf + e * 136 + p);
  }
}

// ---------- flash attention: swapped-operand, dbuf K/V, 1 barrier/iter ----------
__global__ __launch_bounds__(256) void attn_kernel(const f16* __restrict__ Q,
                                                   const f16* __restrict__ K,
                                                   const f16* __restrict__ Vt,
                                                   float* __restrict__ out) {
  __shared__ __align__(16) f16 k_lds[2][64][72];   // [buf][kv][dh]
  __shared__ __align__(16) f16 vt_lds[2][64][72];  // [buf][dh][kv]

  const int blk = blockIdx.x;  // 768
  const int pr = blk & 7;
  const int bh = blk >> 3;
  const int t = threadIdx.x;
  const int wv = t >> 6;
  const int lane = t & 63;
  const int g = lane >> 4;
  const int ql = lane & 15;

  const f16* Qb = Q + (size_t)bh * Sq * DHq;
  const f16* Kb = K + (size_t)bh * Sq * DHq;
  const f16* Vtb = Vt + (size_t)bh * DHq * Sq;
  const int b = bh / Hq, h = bh % Hq;

  const int r0 = t >> 3;          // staging row 0..31 (and +32)
  const int p0 = (t & 7) * 8;     // staging col offset (f16 elems)

  for (int ph = 0; ph < 2; ph++) {
    const int mt = ph ? (15 - pr) : pr;
    const int q0 = mt * 64;
    const int qg = q0 + wv * 16 + ql;  // this lane's q row (global within bh)
    f16x8 qf0 = *reinterpret_cast<const f16x8*>(Qb + (size_t)qg * DHq + g * 8);
    f16x8 qf1 = *reinterpret_cast<const f16x8*>(Qb + (size_t)qg * DHq + 32 + g * 8);

    f32x4 o_acc[4] = {};
    float m_r = -__builtin_inff(), l_r = 0.f;

    uint4 kreg0, kreg1, vreg0, vreg1;
    // stage kt=0 directly
    kreg0 = *reinterpret_cast<const uint4*>(Kb + (size_t)r0 * DHq + p0);
    kreg1 = *reinterpret_cast<const uint4*>(Kb + (size_t)(32 + r0) * DHq + p0);
    vreg0 = *reinterpret_cast<const uint4*>(Vtb + (size_t)r0 * Sq + p0);
    vreg1 = *reinterpret_cast<const uint4*>(Vtb + (size_t)(32 + r0) * Sq + p0);
    *reinterpret_cast<uint4*>(&k_lds[0][r0][p0]) = kreg0;
    *reinterpret_cast<uint4*>(&k_lds[0][32 + r0][p0]) = kreg1;
    *reinterpret_cast<uint4*>(&vt_lds[0][r0][p0]) = vreg0;
    *reinterpret_cast<uint4*>(&vt_lds[0][32 + r0][p0]) = vreg1;
    if (mt >= 1) {  // prefetch kt=1
      kreg0 = *reinterpret_cast<const uint4*>(Kb + (size_t)(64 + r0) * DHq + p0);
      kreg1 = *reinterpret_cast<const uint4*>(Kb + (size_t)(96 + r0) * DHq + p0);
      vreg0 = *reinterpret_cast<const uint4*>(Vtb + (size_t)r0 * Sq + 64 + p0);
      vreg1 = *reinterpret_cast<const uint4*>(Vtb + (size_t)(32 + r0) * Sq + 64 + p0);
    }
    __syncthreads();

    int cur = 0;
    for (int kt = 0; kt <= mt; kt++) {
      // S^T = K Q^T : lane holds q=qg, kv_local = nt*16 + g*4 + r
      f32x4 sf[4] = {};
#pragma unroll
      for (int nt = 0; nt < 4; nt++) {
        f16x8 kf0 = *reinterpret_cast<const f16x8*>(&k_lds[cur][nt * 16 + ql][g * 8]);
        f16x8 kf1 = *reinterpret_cast<const f16x8*>(&k_lds[cur][nt * 16 + ql][32 + g * 8]);
        sf[nt] = MFMA16(kf0, qf0, sf[nt]);
        sf[nt] = MFMA16(kf1, qf1, sf[nt]);
      }

      if (kt == mt) {  // causal mask on the diagonal tile
#pragma unroll
        for (int nt = 0; nt < 4; nt++)
#pragma unroll
          for (int r = 0; r < 4; r++)
            if (nt * 16 + g * 4 + r > wv * 16 + ql) sf[nt][r] = -__builtin_inff();
      }

      // in-lane softmax (exp2 domain): lane owns 16 of 64 kv values of one q-row
      float rowmax = sf[0][0];
#pragma unroll
      for (int nt = 0; nt < 4; nt++)
#pragma unroll
        for (int r = 0; r < 4; r++) rowmax = fmaxf(rowmax, sf[nt][r]);
      rowmax = fmaxf(rowmax, __shfl_xor(rowmax, 16, 64));
      rowmax = fmaxf(rowmax, __shfl_xor(rowmax, 32, 64));
      float mnew = fmaxf(m_r, rowmax);
      float corr = EXP2(m_r - mnew);
      float p[4][4];
      float rs = 0.f;
#pragma unroll
      for (int nt = 0; nt < 4; nt++)
#pragma unroll
        for (int r = 0; r < 4; r++) {
          float pe = EXP2(sf[nt][r] - mnew);
          p[nt][r] = pe;
          rs += pe;
        }
      rs += __shfl_xor(rs, 16, 64);
      rs += __shfl_xor(rs, 32, 64);
      l_r = l_r * corr + rs;
      m_r = mnew;
#pragma unroll
      for (int nt = 0; nt < 4; nt++) {
        o_acc[nt][0] *= corr; o_acc[nt][1] *= corr;
        o_acc[nt][2] *= corr; o_acc[nt][3] *= corr;
      }

      // pack P to f16 pairs: pk[nt][p2] = P[qg][kv = nt*16 + g*4 + 2*p2 + {0,1}]
      uint32_t pk[4][2];
#pragma unroll
      for (int nt = 0; nt < 4; nt++) {
        union { f16 hh[2]; uint32_t u; } z0, z1;
        z0.hh[0] = (f16)p[nt][0]; z0.hh[1] = (f16)p[nt][1];
        z1.hh[0] = (f16)p[nt][2]; z1.hh[1] = (f16)p[nt][3];
        pk[nt][0] = z0.u; pk[nt][1] = z1.u;
      }
      // Redistribute to P^T B-fragments: shuffle BOTH nt candidates, select at dest.
      const int srcA = ((g & 1) * 2) * 16 + ql;
      const int srcB = srcA + 16;
      const bool selhi = (g >> 1) != 0;
      f16x8 pf[2];
#pragma unroll
      for (int ks = 0; ks < 2; ks++) {
        uint32_t aA0 = (uint32_t)__shfl((int)pk[2 * ks][0], srcA, 64);
        uint32_t aA1 = (uint32_t)__shfl((int)pk[2 * ks][1], srcA, 64);
        uint32_t aB0 = (uint32_t)__shfl((int)pk[2 * ks][0], srcB, 64);
        uint32_t aB1 = (uint32_t)__shfl((int)pk[2 * ks][1], srcB, 64);
        uint32_t bA0 = (uint32_t)__shfl((int)pk[2 * ks + 1][0], srcA, 64);
        uint32_t bA1 = (uint32_t)__shfl((int)pk[2 * ks + 1][1], srcA, 64);
        uint32_t bB0 = (uint32_t)__shfl((int)pk[2 * ks + 1][0], srcB, 64);
        uint32_t bB1 = (uint32_t)__shfl((int)pk[2 * ks + 1][1], srcB, 64);
        union { uint32_t w[4]; f16x8 v; } z;
        z.w[0] = selhi ? bA0 : aA0;
        z.w[1] = selhi ? bA1 : aA1;
        z.w[2] = selhi ? bB0 : aB0;
        z.w[3] = selhi ? bB1 : aB1;
        pf[ks] = z.v;
      }

      // O^T += V^T P^T : o_acc[nt] has dh = nt*16 + g*4 + r, q = qg
#pragma unroll
      for (int nt = 0; nt < 4; nt++) {
        f16x8 vf0 = *reinterpret_cast<const f16x8*>(&vt_lds[cur][nt * 16 + ql][g * 8]);
        f16x8 vf1 = *reinterpret_cast<const f16x8*>(&vt_lds[cur][nt * 16 + ql][32 + g * 8]);
        o_acc[nt] = MFMA16(vf0, pf[0], o_acc[nt]);
        o_acc[nt] = MFMA16(vf1, pf[1], o_acc[nt]);
      }

      // write next tile from regs; issue loads for kt+2
      if (kt < mt) {
        *reinterpret_cast<uint4*>(&k_lds[cur ^ 1][r0][p0]) = kreg0;
        *reinterpret_cast<uint4*>(&k_lds[cur ^ 1][32 + r0][p0]) = kreg1;
        *reinterpret_cast<uint4*>(&vt_lds[cur ^ 1][r0][p0]) = vreg0;
        *reinterpret_cast<uint4*>(&vt_lds[cur ^ 1][32 + r0][p0]) = vreg1;
        if (kt + 2 <= mt) {
          const int kv0 = (kt + 2) * 64;
          kreg0 = *reinterpret_cast<const uint4*>(Kb + (size_t)(kv0 + r0) * DHq + p0);
          kreg1 = *reinterpret_cast<const uint4*>(Kb + (size_t)(kv0 + 32 + r0) * DHq + p0);
          vreg0 = *reinterpret_cast<const uint4*>(Vtb + (size_t)r0 * Sq + kv0 + p0);
          vreg1 = *reinterpret_cast<const uint4*>(Vtb + (size_t)(32 + r0) * Sq + kv0 + p0);
        }
      }
      __syncthreads();
      cur ^= 1;
    }

    // epilogue: out[b][q][h*64 + dh], 4 consecutive dh per lane -> float4
    float rl = 1.0f / l_r;
    float* op = out + ((size_t)(b * Sq + qg)) * (Hq * DHq) + h * DHq;
#pragma unroll
    for (int nt = 0; nt < 4; nt++) {
      float4 st = { o_acc[nt][0] * rl, o_acc[nt][1] * rl,
                    o_acc[nt][2] * rl, o_acc[nt][3] * rl };
      *reinterpret_cast<float4*>(op + nt * 16 + g * 4) = st;
    }
  }
}

extern "C" void kernel_launch(void* const* d_in, const int* in_sizes, int n_in,
                              void* d_out, int out_size, void* d_ws, size_t ws_size,
                              hipStream_t stream) {
  const float* x = (const float*)d_in[0];
  const float* Wq = (const float*)d_in[1];
  const float* Wk = (const float*)d_in[2];
  const float* Wv = (const float*)d_in[3];
  float* out = (float*)d_out;

  const size_t off_xb = 0;                    // 8192*768*2      = 12,582,912
  const size_t off_wt = 12582912;             // 2304*768*2      =  3,538,944
  const size_t off_q = 16121856;              // 96*1024*64*2    = 12,582,912
  const size_t off_k = 28704768;
  const size_t off_v = 41287680;
  const size_t need = 53870592;
  if (ws_size < need) return;

  char* ws = (char*)d_ws;
  f16* xh = (f16*)(ws + off_xb);
  f16* WT = (f16*)(ws + off_wt);
  f16* Qd = (f16*)(ws + off_q);
  f16* Kd = (f16*)(ws + off_k);
  f16* Vtd = (f16*)(ws + off_v);

  cvt_x_kernel<<<3072, 256, 0, stream>>>(x, xh);
  cvt_w_kernel<<<6912, 256, 0, stream>>>(Wq, Wk, Wv, WT);
  proj_kernel<<<dim3(64, 12), 256, 0, stream>>>(xh, WT, Qd, Kd, Vtd);
  attn_kernel<<<768, 256, 0, stream>>>(Qd, Kd, Vtd, out);
}

// Round 8
// 85.035 us; speedup vs baseline: 1.2840x; 1.1985x over previous
//
#include <hip/hip_runtime.h>

// MHA forward: x[8,1024,768] fp32; Wq/Wk/Wv[12,768,64] fp32 -> out[8,1024,768] fp32
// cvt x->f16, cvt W->f16T (LDS transpose), QKV proj (f16 MFMA, 3-buffer global_load_lds
// pipeline, counted vmcnt, hoisted incremented addresses, 2-way XOR swizzle),
// flash attn (swapped-operand MFMA, XCD-local (bh,pr) remap, setprio).

#define Bq 8
#define Sq 1024
#define Dq 768
#define Hq 12
#define DHq 64

typedef _Float16 f16;
typedef f16 f16x8 __attribute__((ext_vector_type(8)));
typedef float f32x4 __attribute__((ext_vector_type(4)));

#define MFMA16(a, b, c) __builtin_amdgcn_mfma_f32_16x16x32_f16(a, b, c, 0, 0, 0)

// 0.125 (1/sqrt(64)) * log2(e): folded into Q so attn works in exp2 domain
#define QSCL 0.1803368801111244f

#if __has_builtin(__builtin_amdgcn_exp2f)
#define EXP2(x) __builtin_amdgcn_exp2f(x)
#else
#define EXP2(x) exp2f(x)
#endif

__device__ __forceinline__ void gload16(const f16* g, f16* l) {
  __builtin_amdgcn_global_load_lds(
      (const __attribute__((address_space(1))) void*)g,
      (__attribute__((address_space(3))) void*)l, 16, 0, 0);
}

// ---------- convert x (fp32 -> f16), 8 elems/thread ----------
__global__ __launch_bounds__(256) void cvt_x_kernel(const float* __restrict__ x,
                                                    f16* __restrict__ xh) {
  int i = blockIdx.x * 256 + threadIdx.x;
  const float4* src = reinterpret_cast<const float4*>(x) + i * 2;
  float4 a = src[0], b = src[1];
  f16x8 o;
  o[0] = (f16)a.x; o[1] = (f16)a.y; o[2] = (f16)a.z; o[3] = (f16)a.w;
  o[4] = (f16)b.x; o[5] = (f16)b.y; o[6] = (f16)b.z; o[7] = (f16)b.w;
  *reinterpret_cast<f16x8*>(xh + i * 8) = o;
}

// ---------- convert W -> WT f16 via LDS transpose, layout [w][h][e(64)][k(768)] ----------
// grid (12 ktile, 12 h, 3 w), block 256. Reads coalesced (64 lanes x 4B along e),
// writes coalesced (64 lanes x 2B along k).
__global__ __launch_bounds__(256) void cvt_w_kernel(const float* __restrict__ Wq,
                                                    const float* __restrict__ Wk,
                                                    const float* __restrict__ Wv,
                                                    f16* __restrict__ WT) {
  __shared__ float tile[64][65];
  const int kt = blockIdx.x, h = blockIdx.y, w = blockIdx.z;
  const float* W = (w == 0) ? Wq : (w == 1) ? Wk : Wv;
  const int t = threadIdx.x;
  const int c0 = t & 63, r4 = t >> 6;
#pragma unroll
  for (int i = 0; i < 16; i++) {
    int kr = i * 4 + r4;
    tile[kr][c0] = W[((size_t)h * Dq + kt * 64 + kr) * DHq + c0];
  }
  __syncthreads();
#pragma unroll
  for (int i = 0; i < 16; i++) {
    int e2 = i * 4 + r4;
    WT[((size_t)(w * Hq + h) * DHq + e2) * Dq + kt * 64 + c0] = (f16)tile[c0][e2];
  }
}

// ---------- QKV projection: tile 128x192, BK=32, 3-buffer pipeline, 2Mx2N waves ----------
// LDS rows are 64B (4x16B units); logical unit u of row r stored at u ^ ((r>>1)&3):
// spreads reads over all 8 bank-units (2 lanes/unit = free). Sources pre-swizzled so
// the linear gload_lds DMA lands each unit in its swizzled slot.
// Pipeline: 2-deep prefetch, {vmcnt(5); s_barrier; STAGE(i+2); compute(i)}; pointers
// hoisted and incremented (no per-step address rebuild); fully unrolled so buf is literal.
__global__ __launch_bounds__(256) void proj_kernel(const f16* __restrict__ xh,
                                                   const f16* __restrict__ WT,
                                                   f16* __restrict__ Q,
                                                   f16* __restrict__ K,
                                                   f16* __restrict__ Vt) {
  __shared__ __align__(1024) f16 smem[30720];  // A 3x4096 @0, B 3x6144 @12288

  const int mt = blockIdx.x;  // 0..63
  const int h = blockIdx.y;   // 0..11
  const int row0 = mt * 128;
  const int t = threadIdx.x;
  const int wv = t >> 6;
  const int lane = t & 63;
  const int g = lane >> 4;
  const int ql = lane & 15;
  const int wvm = wv >> 1, wvn = wv & 1;

  const int lr = lane >> 2;                          // row within 16-row chunk
  const int scg = (lane & 3) ^ ((lane >> 3) & 3);    // pre-swizzled source unit

  const f16* xsrc = xh + (size_t)row0 * Dq;
  const f16* wsrc = WT + (size_t)h * DHq * Dq;

  // hoisted per-thread global source pointers (advance +32 elems per staged step)
  const f16* gA0 = xsrc + (size_t)(wv * 32 + lr) * Dq + scg * 8;
  const f16* gA1 = gA0 + (size_t)16 * Dq;
  const int n0 = wv * 48 + lr, n1 = n0 + 16, n2 = n0 + 32;
  const f16* gB0 = wsrc + ((size_t)(n0 >> 6) * Hq * DHq + (n0 & 63)) * Dq + scg * 8;
  const f16* gB1 = wsrc + ((size_t)(n1 >> 6) * Hq * DHq + (n1 & 63)) * Dq + scg * 8;
  const f16* gB2 = wsrc + ((size_t)(n2 >> 6) * Hq * DHq + (n2 & 63)) * Dq + scg * 8;

  f32x4 acc[4][6] = {};

#define PROJ_STAGE(buf)                                              \
  do {                                                               \
    f16* sA_ = smem + (buf) * 4096 + wv * 1024;                      \
    f16* sB_ = smem + 12288 + (buf) * 6144 + wv * 1536;              \
    gload16(gA0, sA_); gload16(gA1, sA_ + 512);                      \
    gload16(gB0, sB_); gload16(gB1, sB_ + 512);                      \
    gload16(gB2, sB_ + 1024);                                        \
    gA0 += 32; gA1 += 32; gB0 += 32; gB1 += 32; gB2 += 32;           \
  } while (0)

  PROJ_STAGE(0);
  PROJ_STAGE(1);

  const int rq = (g ^ ((ql >> 1) & 3)) * 8;  // swizzled read unit offset (elems)
  const f16* rA = smem + (wvm * 64 + ql) * 32 + rq;
  const f16* rB = smem + 12288 + (wvn * 96 + ql) * 32 + rq;

#pragma unroll
  for (int step = 0; step < 24; step++) {
    if (step < 23) asm volatile("s_waitcnt vmcnt(5) lgkmcnt(0)" ::: "memory");
    else           asm volatile("s_waitcnt vmcnt(0) lgkmcnt(0)" ::: "memory");
    __builtin_amdgcn_s_barrier();
    __builtin_amdgcn_sched_barrier(0);
    if (step < 22) PROJ_STAGE((step + 2) % 3);
    const int cur = step % 3;
    f16x8 af[4], bf[6];
#pragma unroll
    for (int mf = 0; mf < 4; mf++)
      af[mf] = *reinterpret_cast<const f16x8*>(rA + cur * 4096 + mf * 512);
#pragma unroll
    for (int nf = 0; nf < 6; nf++)
      bf[nf] = *reinterpret_cast<const f16x8*>(rB + cur * 6144 + nf * 512);
    __builtin_amdgcn_s_setprio(1);
#pragma unroll
    for (int mf = 0; mf < 4; mf++)
#pragma unroll
      for (int nf = 0; nf < 6; nf++)
        acc[mf][nf] = MFMA16(af[mf], bf[nf], acc[mf][nf]);
    __builtin_amdgcn_s_setprio(0);
  }
#undef PROJ_STAGE
  __syncthreads();  // all LDS reads done before smem reuse below

  const int b = row0 >> 10;
  const int s0 = row0 & 1023;
  const size_t base_sd = ((size_t)(b * Hq + h) * Sq) * DHq;

  // Q (pre-scaled) and K: [bh][s][dh]
#pragma unroll
  for (int nf = 0; nf < 6; nf++) {
    const int c = wvn * 96 + nf * 16 + ql;  // output col 0..191
    const int w = c >> 6;                   // 0=Q 1=K 2=V (wave-uniform per nf)
    if (w < 2) {
      f16* dst = (w == 0 ? Q : K);
      const float scl = (w == 0) ? QSCL : 1.0f;
      const int e = c & 63;
#pragma unroll
      for (int mf = 0; mf < 4; mf++) {
        const int sr = wvm * 64 + mf * 16 + g * 4;
#pragma unroll
        for (int r = 0; r < 4; r++)
          dst[base_sd + (size_t)(s0 + sr + r) * DHq + e] = (f16)(acc[mf][nf][r] * scl);
      }
    }
  }

  // V: transpose via smem (vbuf [64 e][136]) then coalesced write to [bh][dh][s]
  f16* vbuf = smem;
#pragma unroll
  for (int nf = 2; nf < 6; nf++) {
    if (wvn == 1) {
      const int e = (96 + nf * 16 + ql) & 63;
#pragma unroll
      for (int mf = 0; mf < 4; mf++) {
        const int sr = wvm * 64 + mf * 16 + g * 4;
        union { f16 hh[4]; uint2 u; } z;
#pragma unroll
        for (int r = 0; r < 4; r++) z.hh[r] = (f16)acc[mf][nf][r];
        *reinterpret_cast<uint2*>(&vbuf[e * 136 + sr]) = z.u;
      }
    }
  }
  __syncthreads();
#pragma unroll
  for (int i = 0; i < 4; i++) {  // 64 e-rows x 128 s = 1024 chunks of 16B
    int c = t + 256 * i;
    int e = c >> 4, p = (c & 15) * 8;
    *reinterpret_cast<uint4*>(Vt + base_sd + (size_t)e * Sq + s0 + p) =
        *reinterpret_cast<const uint4*>(vbuf + e * 136 + p);
  }
}

// ---------- flash attention: swapped-operand, dbuf K/V, XCD-local remap ----------
__global__ __launch_bounds__(256) void attn_kernel(const f16* __restrict__ Q,
                                                   const f16* __restrict__ K,
                                                   const f16* __restrict__ Vt,
                                                   float* __restrict__ out) {
  __shared__ __align__(16) f16 k_lds[2][64][72];   // [buf][kv][dh]
  __shared__ __align__(16) f16 vt_lds[2][64][72];  // [buf][dh][kv]

  // XCD-locality remap: all 8 pr-blocks of one bh share L%8 (same XCD's L2),
  // so each XCD caches only 12 heads' K/V (3 MB < 4 MB L2).
  const int L = blockIdx.x;  // 768
  const int m = L >> 3;
  const int pr = m / Hq;                      // 0..7
  const int bh = (L & 7) * Hq + (m % Hq);     // 0..95
  const int t = threadIdx.x;
  const int wv = t >> 6;
  const int lane = t & 63;
  const int g = lane >> 4;
  const int ql = lane & 15;

  const f16* Qb = Q + (size_t)bh * Sq * DHq;
  const f16* Kb = K + (size_t)bh * Sq * DHq;
  const f16* Vtb = Vt + (size_t)bh * DHq * Sq;
  const int b = bh / Hq, h = bh % Hq;

  const int r0 = t >> 3;          // staging row 0..31 (and +32)
  const int p0 = (t & 7) * 8;     // staging col offset (f16 elems)

  for (int ph = 0; ph < 2; ph++) {
    const int mt = ph ? (15 - pr) : pr;
    const int q0 = mt * 64;
    const int qg = q0 + wv * 16 + ql;  // this lane's q row (global within bh)
    f16x8 qf0 = *reinterpret_cast<const f16x8*>(Qb + (size_t)qg * DHq + g * 8);
    f16x8 qf1 = *reinterpret_cast<const f16x8*>(Qb + (size_t)qg * DHq + 32 + g * 8);

    f32x4 o_acc[4] = {};
    float m_r = -__builtin_inff(), l_r = 0.f;

    uint4 kreg0, kreg1, vreg0, vreg1;
    // stage kt=0 directly
    kreg0 = *reinterpret_cast<const uint4*>(Kb + (size_t)r0 * DHq + p0);
    kreg1 = *reinterpret_cast<const uint4*>(Kb + (size_t)(32 + r0) * DHq + p0);
    vreg0 = *reinterpret_cast<const uint4*>(Vtb + (size_t)r0 * Sq + p0);
    vreg1 = *reinterpret_cast<const uint4*>(Vtb + (size_t)(32 + r0) * Sq + p0);
    *reinterpret_cast<uint4*>(&k_lds[0][r0][p0]) = kreg0;
    *reinterpret_cast<uint4*>(&k_lds[0][32 + r0][p0]) = kreg1;
    *reinterpret_cast<uint4*>(&vt_lds[0][r0][p0]) = vreg0;
    *reinterpret_cast<uint4*>(&vt_lds[0][32 + r0][p0]) = vreg1;
    if (mt >= 1) {  // prefetch kt=1
      kreg0 = *reinterpret_cast<const uint4*>(Kb + (size_t)(64 + r0) * DHq + p0);
      kreg1 = *reinterpret_cast<const uint4*>(Kb + (size_t)(96 + r0) * DHq + p0);
      vreg0 = *reinterpret_cast<const uint4*>(Vtb + (size_t)r0 * Sq + 64 + p0);
      vreg1 = *reinterpret_cast<const uint4*>(Vtb + (size_t)(32 + r0) * Sq + 64 + p0);
    }
    __syncthreads();

    int cur = 0;
    for (int kt = 0; kt <= mt; kt++) {
      // S^T = K Q^T : lane holds q=qg, kv_local = nt*16 + g*4 + r
      f32x4 sf[4] = {};
      __builtin_amdgcn_s_setprio(1);
#pragma unroll
      for (int nt = 0; nt < 4; nt++) {
        f16x8 kf0 = *reinterpret_cast<const f16x8*>(&k_lds[cur][nt * 16 + ql][g * 8]);
        f16x8 kf1 = *reinterpret_cast<const f16x8*>(&k_lds[cur][nt * 16 + ql][32 + g * 8]);
        sf[nt] = MFMA16(kf0, qf0, sf[nt]);
        sf[nt] = MFMA16(kf1, qf1, sf[nt]);
      }
      __builtin_amdgcn_s_setprio(0);

      if (kt == mt) {  // causal mask on the diagonal tile
#pragma unroll
        for (int nt = 0; nt < 4; nt++)
#pragma unroll
          for (int r = 0; r < 4; r++)
            if (nt * 16 + g * 4 + r > wv * 16 + ql) sf[nt][r] = -__builtin_inff();
      }

      // in-lane softmax (exp2 domain): lane owns 16 of 64 kv values of one q-row
      float rowmax = sf[0][0];
#pragma unroll
      for (int nt = 0; nt < 4; nt++)
#pragma unroll
        for (int r = 0; r < 4; r++) rowmax = fmaxf(rowmax, sf[nt][r]);
      rowmax = fmaxf(rowmax, __shfl_xor(rowmax, 16, 64));
      rowmax = fmaxf(rowmax, __shfl_xor(rowmax, 32, 64));
      float mnew = fmaxf(m_r, rowmax);
      float corr = EXP2(m_r - mnew);
      float p[4][4];
      float rs = 0.f;
#pragma unroll
      for (int nt = 0; nt < 4; nt++)
#pragma unroll
        for (int r = 0; r < 4; r++) {
          float pe = EXP2(sf[nt][r] - mnew);
          p[nt][r] = pe;
          rs += pe;
        }
      rs += __shfl_xor(rs, 16, 64);
      rs += __shfl_xor(rs, 32, 64);
      l_r = l_r * corr + rs;
      m_r = mnew;
#pragma unroll
      for (int nt = 0; nt < 4; nt++) {
        o_acc[nt][0] *= corr; o_acc[nt][1] *= corr;
        o_acc[nt][2] *= corr; o_acc[nt][3] *= corr;
      }

      // pack P to f16 pairs: pk[nt][p2] = P[qg][kv = nt*16 + g*4 + 2*p2 + {0,1}]
      uint32_t pk[4][2];
#pragma unroll
      for (int nt = 0; nt < 4; nt++) {
        union { f16 hh[2]; uint32_t u; } z0, z1;
        z0.hh[0] = (f16)p[nt][0]; z0.hh[1] = (f16)p[nt][1];
        z1.hh[0] = (f16)p[nt][2]; z1.hh[1] = (f16)p[nt][3];
        pk[nt][0] = z0.u; pk[nt][1] = z1.u;
      }
      // Redistribute to P^T B-fragments: shuffle BOTH nt candidates, select at dest.
      const int srcA = ((g & 1) * 2) * 16 + ql;
      const int srcB = srcA + 16;
      const bool selhi = (g >> 1) != 0;
      f16x8 pf[2];
#pragma unroll
      for (int ks = 0; ks < 2; ks++) {
        uint32_t aA0 = (uint32_t)__shfl((int)pk[2 * ks][0], srcA, 64);
        uint32_t aA1 = (uint32_t)__shfl((int)pk[2 * ks][1], srcA, 64);
        uint32_t aB0 = (uint32_t)__shfl((int)pk[2 * ks][0], srcB, 64);
        uint32_t aB1 = (uint32_t)__shfl((int)pk[2 * ks][1], srcB, 64);
        uint32_t bA0 = (uint32_t)__shfl((int)pk[2 * ks + 1][0], srcA, 64);
        uint32_t bA1 = (uint32_t)__shfl((int)pk[2 * ks + 1][1], srcA, 64);
        uint32_t bB0 = (uint32_t)__shfl((int)pk[2 * ks + 1][0], srcB, 64);
        uint32_t bB1 = (uint32_t)__shfl((int)pk[2 * ks + 1][1], srcB, 64);
        union { uint32_t w[4]; f16x8 v; } z;
        z.w[0] = selhi ? bA0 : aA0;
        z.w[1] = selhi ? bA1 : aA1;
        z.w[2] = selhi ? bB0 : aB0;
        z.w[3] = selhi ? bB1 : aB1;
        pf[ks] = z.v;
      }

      // O^T += V^T P^T : o_acc[nt] has dh = nt*16 + g*4 + r, q = qg
      __builtin_amdgcn_s_setprio(1);
#pragma unroll
      for (int nt = 0; nt < 4; nt++) {
        f16x8 vf0 = *reinterpret_cast<const f16x8*>(&vt_lds[cur][nt * 16 + ql][g * 8]);
        f16x8 vf1 = *reinterpret_cast<const f16x8*>(&vt_lds[cur][nt * 16 + ql][32 + g * 8]);
        o_acc[nt] = MFMA16(vf0, pf[0], o_acc[nt]);
        o_acc[nt] = MFMA16(vf1, pf[1], o_acc[nt]);
      }
      __builtin_amdgcn_s_setprio(0);

      // write next tile from regs; issue loads for kt+2
      if (kt < mt) {
        *reinterpret_cast<uint4*>(&k_lds[cur ^ 1][r0][p0]) = kreg0;
        *reinterpret_cast<uint4*>(&k_lds[cur ^ 1][32 + r0][p0]) = kreg1;
        *reinterpret_cast<uint4*>(&vt_lds[cur ^ 1][r0][p0]) = vreg0;
        *reinterpret_cast<uint4*>(&vt_lds[cur ^ 1][32 + r0][p0]) = vreg1;
        if (kt + 2 <= mt) {
          const int kv0 = (kt + 2) * 64;
          kreg0 = *reinterpret_cast<const uint4*>(Kb + (size_t)(kv0 + r0) * DHq + p0);
          kreg1 = *reinterpret_cast<const uint4*>(Kb + (size_t)(kv0 + 32 + r0) * DHq + p0);
          vreg0 = *reinterpret_cast<const uint4*>(Vtb + (size_t)r0 * Sq + kv0 + p0);
          vreg1 = *reinterpret_cast<const uint4*>(Vtb + (size_t)(32 + r0) * Sq + kv0 + p0);
        }
      }
      __syncthreads();
      cur ^= 1;
    }

    // epilogue: out[b][q][h*64 + dh], 4 consecutive dh per lane -> float4
    float rl = 1.0f / l_r;
    float* op = out + ((size_t)(b * Sq + qg)) * (Hq * DHq) + h * DHq;
#pragma unroll
    for (int nt = 0; nt < 4; nt++) {
      float4 st = { o_acc[nt][0] * rl, o_acc[nt][1] * rl,
                    o_acc[nt][2] * rl, o_acc[nt][3] * rl };
      *reinterpret_cast<float4*>(op + nt * 16 + g * 4) = st;
    }
  }
}

extern "C" void kernel_launch(void* const* d_in, const int* in_sizes, int n_in,
                              void* d_out, int out_size, void* d_ws, size_t ws_size,
                              hipStream_t stream) {
  const float* x = (const float*)d_in[0];
  const float* Wq = (const float*)d_in[1];
  const float* Wk = (const float*)d_in[2];
  const float* Wv = (const float*)d_in[3];
  float* out = (float*)d_out;

  const size_t off_xb = 0;                    // 8192*768*2      = 12,582,912
  const size_t off_wt = 12582912;             // 2304*768*2      =  3,538,944
  const size_t off_q = 16121856;              // 96*1024*64*2    = 12,582,912
  const size_t off_k = 28704768;
  const size_t off_v = 41287680;
  const size_t need = 53870592;
  if (ws_size < need) return;

  char* ws = (char*)d_ws;
  f16* xh = (f16*)(ws + off_xb);
  f16* WT = (f16*)(ws + off_wt);
  f16* Qd = (f16*)(ws + off_q);
  f16* Kd = (f16*)(ws + off_k);
  f16* Vtd = (f16*)(ws + off_v);

  cvt_x_kernel<<<3072, 256, 0, stream>>>(x, xh);
  cvt_w_kernel<<<dim3(12, 12, 3), 256, 0, stream>>>(Wq, Wk, Wv, WT);
  proj_kernel<<<dim3(64, 12), 256, 0, stream>>>(xh, WT, Qd, Kd, Vtd);
  attn_kernel<<<768, 256, 0, stream>>>(Qd, Kd, Vtd, out);
}